// Round 3
// baseline (281.838 us; speedup 1.0000x reference)
//
#include <hip/hip_runtime.h>

#define DIMC 64
#define KS 7
#define NTAP (KS*KS)      // 49
#define GCH 8             // channels per group
#define NG 8              // groups
#define CMID 32
#define PADD 3
#define HH 128
#define WW 128
#define PLANE (HH*WW)
#define TW 32
#define TH 8
#define TPX (TW+2*PADD)   // 38
#define TPY (TH+2*PADD)   // 14
#define NPIX (TPX*TPY)    // 532
#define CPAD 12

// One block = one (batch, group, 32x8 tile). 2048 blocks total.
// LDS 25.5 KB -> 6 blocks/CU resident -> ~24 waves/CU (vs 4 before).
__global__ __launch_bounds__(256, 6)
void invol_g_kernel(const float* __restrict__ x, const float* __restrict__ y,
                    const float* __restrict__ w1, const float* __restrict__ b1,
                    const float* __restrict__ w2, const float* __restrict__ b2,
                    float* __restrict__ out) {
    __shared__ float ytile[NPIX * CPAD];   // 25.5 KB

    const int tid = threadIdx.x;
    const int tx = tid & 31;
    const int ty = tid >> 5;
    const int bx = blockIdx.x, by = blockIdx.y;
    const int bz = blockIdx.z >> 3;        // batch
    const int g  = blockIdx.z & 7;         // group
    const int gx = bx * TW + tx;
    const int gy = by * TH + ty;

    // ---- stage y halo tile for this group's 8 channels (issue loads early;
    //      their latency hides under the mid matvec below) ----
    for (int i = tid; i < NPIX * GCH; i += 256) {
        int c = i / NPIX;
        int p = i - c * NPIX;
        int r = p / TPX;
        int col = p - r * TPX;
        int sy = by * TH + r - PADD;
        int sx = bx * TW + col - PADD;
        float v = 0.f;
        if (sy >= 0 && sy < HH && sx >= 0 && sx < WW)
            v = y[((size_t)(bz * DIMC + g * GCH + c) * HH + sy) * WW + sx];
        ytile[p * CPAD + c] = v;
    }

    // ---- mid[32] = w1 @ x(:,pixel) + b1 (recomputed per group-block) ----
    float mid[CMID];
    {
        const float* xp = x + ((size_t)(bz * DIMC) * HH + gy) * WW + gx;
        #pragma unroll
        for (int m = 0; m < CMID; ++m) mid[m] = b1[m];
        #pragma unroll
        for (int cq = 0; cq < DIMC / 4; ++cq) {
            float x0 = xp[(4*cq+0) * PLANE];
            float x1 = xp[(4*cq+1) * PLANE];
            float x2 = xp[(4*cq+2) * PLANE];
            float x3 = xp[(4*cq+3) * PLANE];
            #pragma unroll
            for (int m = 0; m < CMID; ++m) {
                const float4 wv = *reinterpret_cast<const float4*>(w1 + m * DIMC + 4*cq);
                mid[m] = fmaf(wv.x, x0, mid[m]);
                mid[m] = fmaf(wv.y, x1, mid[m]);
                mid[m] = fmaf(wv.z, x2, mid[m]);
                mid[m] = fmaf(wv.w, x3, mid[m]);
            }
        }
    }

    __syncthreads();

    // ---- wt[kk] = b2[g*49+kk] + w2[g*49+kk,:] . mid ----
    float wt[NTAP];
    const float*  b2g = b2 + g * NTAP;
    const float4* w2g = reinterpret_cast<const float4*>(w2 + g * NTAP * CMID);
    #pragma unroll
    for (int kk = 0; kk < NTAP; ++kk) {
        float a = b2g[kk];
        #pragma unroll
        for (int mq = 0; mq < CMID / 4; ++mq) {
            float4 wv = w2g[kk * (CMID / 4) + mq];
            a = fmaf(wv.x, mid[4*mq+0], a);
            a = fmaf(wv.y, mid[4*mq+1], a);
            a = fmaf(wv.z, mid[4*mq+2], a);
            a = fmaf(wv.w, mid[4*mq+3], a);
        }
        wt[kk] = a;
    }

    // ---- involution accumulate: 8 channels x 49 taps from LDS ----
    float acc[GCH];
    #pragma unroll
    for (int cc = 0; cc < GCH; ++cc) acc[cc] = 0.f;
    #pragma unroll
    for (int ky = 0; ky < KS; ++ky) {
        #pragma unroll
        for (int kx = 0; kx < KS; ++kx) {
            float wv = wt[ky * KS + kx];
            int pp = (ty + ky) * TPX + (tx + kx);
            const float4* yr = reinterpret_cast<const float4*>(&ytile[pp * CPAD]);
            float4 ya = yr[0];
            float4 yb = yr[1];
            acc[0] = fmaf(wv, ya.x, acc[0]);
            acc[1] = fmaf(wv, ya.y, acc[1]);
            acc[2] = fmaf(wv, ya.z, acc[2]);
            acc[3] = fmaf(wv, ya.w, acc[3]);
            acc[4] = fmaf(wv, yb.x, acc[4]);
            acc[5] = fmaf(wv, yb.y, acc[5]);
            acc[6] = fmaf(wv, yb.z, acc[6]);
            acc[7] = fmaf(wv, yb.w, acc[7]);
        }
    }

    float* op = out + ((size_t)(bz * DIMC + g * GCH) * HH + gy) * WW + gx;
    #pragma unroll
    for (int cc = 0; cc < GCH; ++cc) op[cc * PLANE] = acc[cc];
}

extern "C" void kernel_launch(void* const* d_in, const int* in_sizes, int n_in,
                              void* d_out, int out_size, void* d_ws, size_t ws_size,
                              hipStream_t stream) {
    const float* x  = (const float*)d_in[0];
    const float* y  = (const float*)d_in[1];
    const float* w1 = (const float*)d_in[2];
    const float* b1 = (const float*)d_in[3];
    const float* w2 = (const float*)d_in[4];
    const float* b2 = (const float*)d_in[5];
    float* out = (float*)d_out;

    dim3 grid(WW / TW, HH / TH, 4 * NG);
    dim3 block(256);
    hipLaunchKernelGGL(invol_g_kernel, grid, block, 0, stream,
                       x, y, w1, b1, w2, b2, out);
}

// Round 4
// 71.089 us; speedup vs baseline: 3.9646x; 3.9646x over previous
//
#include <hip/hip_runtime.h>

#define DIMC 64
#define KS 7
#define NTAP (KS*KS)      // 49
#define GCH 8
#define NG 8
#define CMID 32
#define PADD 3
#define HH 128
#define WW 128
#define PLANE (HH*WW)
#define TW 32
#define TH 8
#define TPX (TW+2*PADD)   // 38
#define TPY (TH+2*PADD)   // 14
#define NPIX (TPX*TPY)    // 532
#define CPAD 12
#define NB 4
#define MIDWS_BYTES ((size_t)NB * CMID * PLANE * 4)   // 8.39 MB fp32

// ---------------- Kernel A: mid = w1 @ x + b1, once per pixel ----------------
// Layout: midws[((b*8 + q)*PLANE + pix)*4 + j] holds mid[m = q*4+j].
// Grid (64 pixel-blocks, 4 batches, 4 m-chunks) = 1024 blocks -> 4 waves/SIMD.
__global__ __launch_bounds__(256)
void midgen_kernel(const float* __restrict__ x, const float* __restrict__ w1,
                   const float* __restrict__ b1, float* __restrict__ midws) {
    const int pix = blockIdx.x * 256 + threadIdx.x;   // 0..16383 within batch
    const int b  = blockIdx.y;
    const int ch = blockIdx.z;                        // m in [ch*8, ch*8+8)

    const float* xp = x + (size_t)b * DIMC * PLANE + pix;
    float xv[DIMC];
    #pragma unroll
    for (int c = 0; c < DIMC; ++c) xv[c] = xp[(size_t)c * PLANE];

    float m[8];
    #pragma unroll
    for (int j = 0; j < 8; ++j) {
        const float* w1r = w1 + (ch * 8 + j) * DIMC;  // uniform -> s_load
        float a = b1[ch * 8 + j];
        #pragma unroll
        for (int c = 0; c < DIMC; ++c) a = fmaf(w1r[c], xv[c], a);
        m[j] = a;
    }

    float4* o0 = reinterpret_cast<float4*>(midws + (((size_t)b * 8 + ch * 2 + 0) * PLANE + pix) * 4);
    float4* o1 = reinterpret_cast<float4*>(midws + (((size_t)b * 8 + ch * 2 + 1) * PLANE + pix) * 4);
    *o0 = make_float4(m[0], m[1], m[2], m[3]);
    *o1 = make_float4(m[4], m[5], m[6], m[7]);
}

// ---------------- Kernel B: per (batch, group, 32x8 tile) involution ---------
// 2048 blocks, LDS 25.5 KB -> 6 blocks/CU, VGPR cap 128 (no spill expected).
__global__ __launch_bounds__(256, 4)
void invol_kernel(const float* __restrict__ y, const float* __restrict__ midws,
                  const float* __restrict__ w2, const float* __restrict__ b2,
                  float* __restrict__ out) {
    __shared__ float ytile[NPIX * CPAD];   // 25.5 KB

    const int tid = threadIdx.x;
    const int tx = tid & 31, ty = tid >> 5;
    const int bx = blockIdx.x, by = blockIdx.y;
    const int b = blockIdx.z >> 3, g = blockIdx.z & 7;
    const int gx = bx * TW + tx, gy = by * TH + ty;
    const int pix = gy * WW + gx;

    // stage y halo tile (8 channels, zero-padded) -- issue early
    for (int i = tid; i < NPIX * GCH; i += 256) {
        int c = i / NPIX;
        int p = i - c * NPIX;
        int r = p / TPX;
        int col = p - r * TPX;
        int sy = by * TH + r - PADD;
        int sx = bx * TW + col - PADD;
        float v = 0.f;
        if (sy >= 0 && sy < HH && sx >= 0 && sx < WW)
            v = y[((size_t)(b * DIMC + g * GCH + c) * HH + sy) * WW + sx];
        ytile[p * CPAD + c] = v;
    }

    // load mid (8 x float4, coalesced, L2-resident)
    float4 m4[8];
    #pragma unroll
    for (int q = 0; q < 8; ++q)
        m4[q] = *reinterpret_cast<const float4*>(midws + (((size_t)b * 8 + q) * PLANE + pix) * 4);

    // wt[kk] = b2[g*49+kk] + w2[g*49+kk,:] . mid   (w2/b2 uniform -> scalar loads)
    float wt[NTAP];
    const float* w2g = w2 + g * NTAP * CMID;
    const float* b2g = b2 + g * NTAP;
    #pragma unroll
    for (int kk = 0; kk < NTAP; ++kk) {
        const float* wr = w2g + kk * CMID;
        float a = b2g[kk];
        #pragma unroll
        for (int q = 0; q < 8; ++q) {
            a = fmaf(wr[q * 4 + 0], m4[q].x, a);
            a = fmaf(wr[q * 4 + 1], m4[q].y, a);
            a = fmaf(wr[q * 4 + 2], m4[q].z, a);
            a = fmaf(wr[q * 4 + 3], m4[q].w, a);
        }
        wt[kk] = a;
    }

    __syncthreads();

    // involution: 8 channels x 49 taps from LDS
    float acc[GCH];
    #pragma unroll
    for (int cc = 0; cc < GCH; ++cc) acc[cc] = 0.f;
    #pragma unroll
    for (int ky = 0; ky < KS; ++ky) {
        #pragma unroll
        for (int kx = 0; kx < KS; ++kx) {
            float wv = wt[ky * KS + kx];
            int pp = (ty + ky) * TPX + (tx + kx);
            const float4* yr = reinterpret_cast<const float4*>(&ytile[pp * CPAD]);
            float4 ya = yr[0];
            float4 yb = yr[1];
            acc[0] = fmaf(wv, ya.x, acc[0]);
            acc[1] = fmaf(wv, ya.y, acc[1]);
            acc[2] = fmaf(wv, ya.z, acc[2]);
            acc[3] = fmaf(wv, ya.w, acc[3]);
            acc[4] = fmaf(wv, yb.x, acc[4]);
            acc[5] = fmaf(wv, yb.y, acc[5]);
            acc[6] = fmaf(wv, yb.z, acc[6]);
            acc[7] = fmaf(wv, yb.w, acc[7]);
        }
    }

    float* op = out + ((size_t)(b * DIMC + g * GCH) * HH + gy) * WW + gx;
    #pragma unroll
    for (int cc = 0; cc < GCH; ++cc) op[cc * PLANE] = acc[cc];
}

// ---------------- Fallback (known-good R2 fused kernel) ----------------------
__global__ __launch_bounds__(256, 1)
void invol_fused_kernel(const float* __restrict__ x, const float* __restrict__ y,
                        const float* __restrict__ w1, const float* __restrict__ b1,
                        const float* __restrict__ w2, const float* __restrict__ b2,
                        float* __restrict__ out) {
    __shared__ float ytile[NPIX * CPAD];
    const int tid = threadIdx.x;
    const int tx = tid & 31, ty = tid >> 5;
    const int bx = blockIdx.x, by = blockIdx.y, bz = blockIdx.z;
    const int gx = bx * TW + tx, gy = by * TH + ty;

    float xv[DIMC];
    const float* xp = x + ((size_t)(bz * DIMC) * HH + gy) * WW + gx;
    #pragma unroll
    for (int c = 0; c < DIMC; ++c) xv[c] = xp[c * PLANE];

    float mid[CMID];
    #pragma unroll
    for (int m = 0; m < CMID; ++m) {
        float a = b1[m];
        const float4* w1r = reinterpret_cast<const float4*>(w1 + m * DIMC);
        #pragma unroll
        for (int cq = 0; cq < DIMC / 4; ++cq) {
            float4 wv = w1r[cq];
            a = fmaf(wv.x, xv[4*cq+0], a);
            a = fmaf(wv.y, xv[4*cq+1], a);
            a = fmaf(wv.z, xv[4*cq+2], a);
            a = fmaf(wv.w, xv[4*cq+3], a);
        }
        mid[m] = a;
    }

    for (int g = 0; g < NG; ++g) {
        __syncthreads();
        for (int i = tid; i < NPIX * GCH; i += 256) {
            int c = i / NPIX;
            int p = i - c * NPIX;
            int r = p / TPX;
            int col = p - r * TPX;
            int sy = by * TH + r - PADD;
            int sx = bx * TW + col - PADD;
            float v = 0.f;
            if (sy >= 0 && sy < HH && sx >= 0 && sx < WW)
                v = y[((size_t)(bz * DIMC + g * GCH + c) * HH + sy) * WW + sx];
            ytile[p * CPAD + c] = v;
        }
        __syncthreads();

        float wt[NTAP];
        const float*  b2g = b2 + g * NTAP;
        const float4* w2g = reinterpret_cast<const float4*>(w2 + g * NTAP * CMID);
        #pragma unroll
        for (int kk = 0; kk < NTAP; ++kk) {
            float a = b2g[kk];
            #pragma unroll
            for (int mq = 0; mq < CMID / 4; ++mq) {
                float4 wv = w2g[kk * (CMID / 4) + mq];
                a = fmaf(wv.x, mid[4*mq+0], a);
                a = fmaf(wv.y, mid[4*mq+1], a);
                a = fmaf(wv.z, mid[4*mq+2], a);
                a = fmaf(wv.w, mid[4*mq+3], a);
            }
            wt[kk] = a;
        }

        float acc[GCH];
        #pragma unroll
        for (int cc = 0; cc < GCH; ++cc) acc[cc] = 0.f;
        #pragma unroll
        for (int ky = 0; ky < KS; ++ky) {
            #pragma unroll
            for (int kx = 0; kx < KS; ++kx) {
                float wv = wt[ky * KS + kx];
                int pp = (ty + ky) * TPX + (tx + kx);
                const float4* yr = reinterpret_cast<const float4*>(&ytile[pp * CPAD]);
                float4 ya = yr[0];
                float4 yb = yr[1];
                acc[0] = fmaf(wv, ya.x, acc[0]);
                acc[1] = fmaf(wv, ya.y, acc[1]);
                acc[2] = fmaf(wv, ya.z, acc[2]);
                acc[3] = fmaf(wv, ya.w, acc[3]);
                acc[4] = fmaf(wv, yb.x, acc[4]);
                acc[5] = fmaf(wv, yb.y, acc[5]);
                acc[6] = fmaf(wv, yb.z, acc[6]);
                acc[7] = fmaf(wv, yb.w, acc[7]);
            }
        }

        float* op = out + ((size_t)(bz * DIMC + g * GCH) * HH + gy) * WW + gx;
        #pragma unroll
        for (int cc = 0; cc < GCH; ++cc) op[cc * PLANE] = acc[cc];
    }
}

extern "C" void kernel_launch(void* const* d_in, const int* in_sizes, int n_in,
                              void* d_out, int out_size, void* d_ws, size_t ws_size,
                              hipStream_t stream) {
    const float* x  = (const float*)d_in[0];
    const float* y  = (const float*)d_in[1];
    const float* w1 = (const float*)d_in[2];
    const float* b1 = (const float*)d_in[3];
    const float* w2 = (const float*)d_in[4];
    const float* b2 = (const float*)d_in[5];
    float* out = (float*)d_out;

    if (ws_size >= MIDWS_BYTES) {
        float* midws = (float*)d_ws;
        dim3 gridA(PLANE / 256, NB, 4);
        hipLaunchKernelGGL(midgen_kernel, gridA, dim3(256), 0, stream,
                           x, w1, b1, midws);
        dim3 gridB(WW / TW, HH / TH, NB * NG);
        hipLaunchKernelGGL(invol_kernel, gridB, dim3(256), 0, stream,
                           y, midws, w2, b2, out);
    } else {
        dim3 grid(WW / TW, HH / TH, NB);
        hipLaunchKernelGGL(invol_fused_kernel, grid, dim3(256), 0, stream,
                           x, y, w1, b1, w2, b2, out);
    }
}

// Round 6
// 48.396 us; speedup vs baseline: 5.8236x; 1.4689x over previous
//
#include <hip/hip_runtime.h>
#include <hip/hip_bf16.h>
#include <hip/hip_fp16.h>

#define DIMC 64
#define KS 7
#define NTAP 49
#define GCH 8
#define NG 8
#define CMID 32
#define PADD 3
#define HH 128
#define WW 128
#define PLANE (HH*WW)
#define TW 32
#define TH 8
#define TPX (TW+2*PADD)   // 38
#define TPY (TH+2*PADD)   // 14
#define NPIX (TPX*TPY)    // 532
#define NB 4
#define WTSTR 52          // padded wt row stride (f16 units)
#define MIDWS_BYTES ((size_t)NB * PLANE * CMID * 2)   // 4.19 MB bf16

typedef __attribute__((ext_vector_type(8))) short short8;
typedef __attribute__((ext_vector_type(4))) float f32x4;
typedef __fp16 fp16x2 __attribute__((ext_vector_type(2)));

static __device__ inline unsigned short f2bs(float f) {   // fp32 -> bf16 (RNE)
    union { float f; unsigned u; } v; v.f = f;
    unsigned r = v.u + 0x7fff + ((v.u >> 16) & 1);
    return (unsigned short)(r >> 16);
}

static __device__ inline unsigned pkh(float a, float b) { // 2x fp32 -> packed f16 (RTZ)
    union { fp16x2 h; unsigned u; } c;
    c.h = __builtin_amdgcn_cvt_pkrtz(a, b);
    return c.u;
}

// ---------- Kernel A: mid = w1@x + b1, bf16 output in [pix][k] layout ----------
__global__ __launch_bounds__(256)
void midgen_kernel(const float* __restrict__ x, const float* __restrict__ w1,
                   const float* __restrict__ b1, unsigned short* __restrict__ midws) {
    const int pix = blockIdx.x * 256 + threadIdx.x;
    const int b  = blockIdx.y;
    const int ch = blockIdx.z;                       // k-chunk: k = ch*8 + j

    const float* xp = x + (size_t)b * DIMC * PLANE + pix;
    float xv[DIMC];
    #pragma unroll
    for (int c = 0; c < DIMC; ++c) xv[c] = xp[(size_t)c * PLANE];

    unsigned pk[4];
    #pragma unroll
    for (int jj = 0; jj < 4; ++jj) {
        float m0 = b1[ch * 8 + 2 * jj];
        float m1 = b1[ch * 8 + 2 * jj + 1];
        const float* w1r0 = w1 + (ch * 8 + 2 * jj) * DIMC;
        const float* w1r1 = w1r0 + DIMC;
        #pragma unroll
        for (int c = 0; c < DIMC; ++c) {
            m0 = fmaf(w1r0[c], xv[c], m0);
            m1 = fmaf(w1r1[c], xv[c], m1);
        }
        pk[jj] = ((unsigned)f2bs(m1) << 16) | (unsigned)f2bs(m0);
    }
    *reinterpret_cast<uint4*>(midws + ((size_t)b * PLANE + pix) * CMID + ch * 8) =
        make_uint4(pk[0], pk[1], pk[2], pk[3]);
}

// ---------- Kernel B: MFMA wt-GEMM + f16 involution ----------
__global__ __launch_bounds__(256, 4)
void invol_mfma_kernel(const float* __restrict__ y, const unsigned short* __restrict__ midws,
                       const float* __restrict__ w2, const float* __restrict__ b2,
                       float* __restrict__ out) {
    __shared__ __half ytile[NPIX * GCH];     // 8512 B, [px][8ch] f16
    __shared__ __half wtl[256 * WTSTR];      // 26624 B, [px][52] f16

    const int tid = threadIdx.x;
    const int l = tid & 63, w = tid >> 6;
    const int bx = blockIdx.x, by = blockIdx.y;
    const int b = blockIdx.z >> 3, g = blockIdx.z & 7;

    // ---- stage y halo as f16 (4 channels per item, coalesced loads) ----
    #pragma unroll
    for (int k = 0; k < 5; ++k) {
        int i = tid + k * 256;
        if (i < NPIX * 2) {
            int q  = i / NPIX;              // 0 or 1
            int px = i - q * NPIX;
            int c0 = q * 4;
            int r = px / TPX, col = px - r * TPX;
            int sy = by * TH + r - PADD, sx = bx * TW + col - PADD;
            bool ok = (sy >= 0 && sy < HH && sx >= 0 && sx < WW);
            const float* yp = y + ((size_t)(b * DIMC + g * GCH + c0) * HH + sy) * WW + sx;
            float v0 = ok ? yp[0] : 0.f;
            float v1 = ok ? yp[PLANE] : 0.f;
            float v2 = ok ? yp[2 * PLANE] : 0.f;
            float v3 = ok ? yp[3 * PLANE] : 0.f;
            *reinterpret_cast<uint2*>(&ytile[px * GCH + c0]) =
                make_uint2(pkh(v0, v1), pkh(v2, v3));
        }
    }

    // ---- A-fragments: W2g rows (fp32 -> bf16), rows >=49 zeroed ----
    const int fr = l & 15, fk = l >> 4;     // frag row/col, k-chunk
    short8 afrag[4];
    #pragma unroll
    for (int mt = 0; mt < 4; ++mt) {
        short8 af;
        #pragma unroll
        for (int j = 0; j < 8; ++j) af[j] = 0;
        int row = mt * 16 + fr;
        if (row < NTAP) {
            const float* wr = w2 + ((size_t)(g * NTAP + row)) * CMID + fk * 8;
            float4 a0 = *reinterpret_cast<const float4*>(wr);
            float4 a1 = *reinterpret_cast<const float4*>(wr + 4);
            af[0] = (short)f2bs(a0.x); af[1] = (short)f2bs(a0.y);
            af[2] = (short)f2bs(a0.z); af[3] = (short)f2bs(a0.w);
            af[4] = (short)f2bs(a1.x); af[5] = (short)f2bs(a1.y);
            af[6] = (short)f2bs(a1.z); af[7] = (short)f2bs(a1.w);
        }
        afrag[mt] = af;
    }

    // ---- B-fragments: mid bf16 [pix][k], 16B per lane ----
    short8 bfrag[4];
    #pragma unroll
    for (int nt = 0; nt < 4; ++nt) {
        int lp = w * 64 + nt * 16 + fr;                 // local pixel 0..255
        int gy = by * TH + (lp >> 5), gx = bx * TW + (lp & 31);
        const unsigned short* mp = midws + ((size_t)b * PLANE + gy * WW + gx) * CMID + fk * 8;
        union { uint4 u; short8 s; } cv;
        cv.u = *reinterpret_cast<const uint4*>(mp);
        bfrag[nt] = cv.s;
    }

    // ---- GEMM: wt[64pad][256] = W2g @ mid ----
    f32x4 acc[4][4];
    #pragma unroll
    for (int mt = 0; mt < 4; ++mt)
        #pragma unroll
        for (int nt = 0; nt < 4; ++nt) {
            f32x4 z = {0.f, 0.f, 0.f, 0.f};
            acc[mt][nt] = __builtin_amdgcn_mfma_f32_16x16x32_bf16(afrag[mt], bfrag[nt], z, 0, 0, 0);
        }

    // ---- C -> wt_lds (f16). C layout: col=lane&15, row=(lane>>4)*4+reg ----
    const int crow4 = fk * 4;
    #pragma unroll
    for (int mt = 0; mt < 4; ++mt) {
        if (mt < 3 || crow4 == 0) {        // rows > 48 are pad/garbage, skip
            int r0 = mt * 16 + crow4;
            #pragma unroll
            for (int nt = 0; nt < 4; ++nt) {
                int lp = w * 64 + nt * 16 + fr;
                *reinterpret_cast<uint2*>(&wtl[lp * WTSTR + r0]) =
                    make_uint2(pkh(acc[mt][nt][0], acc[mt][nt][1]),
                               pkh(acc[mt][nt][2], acc[mt][nt][3]));
            }
        }
    }

    __syncthreads();

    // ---- read own wt row, add bias ----
    float wtf[52];
    const float* b2g = b2 + g * NTAP;
    const __half2* wrow = reinterpret_cast<const __half2*>(&wtl[tid * WTSTR]);
    #pragma unroll
    for (int q = 0; q < 26; ++q) {
        __half2 h = wrow[q];
        wtf[2 * q]     = __low2float(h);
        wtf[2 * q + 1] = __high2float(h);
    }
    #pragma unroll
    for (int kk = 0; kk < NTAP; ++kk) wtf[kk] += b2g[kk];

    // ---- involution: 49 taps x 8 f16 channels per ds_read_b128 ----
    const int tx = tid & 31, ty = tid >> 5;
    float acco[GCH];
    #pragma unroll
    for (int cc = 0; cc < GCH; ++cc) acco[cc] = 0.f;
    #pragma unroll
    for (int ky = 0; ky < KS; ++ky) {
        #pragma unroll
        for (int kx = 0; kx < KS; ++kx) {
            float wv = wtf[ky * KS + kx];
            int pp = (ty + ky) * TPX + (tx + kx);
            union { uint4 u; __half2 h[4]; } yv;
            yv.u = *reinterpret_cast<const uint4*>(&ytile[pp * GCH]);
            acco[0] = fmaf(wv, __low2float(yv.h[0]),  acco[0]);
            acco[1] = fmaf(wv, __high2float(yv.h[0]), acco[1]);
            acco[2] = fmaf(wv, __low2float(yv.h[1]),  acco[2]);
            acco[3] = fmaf(wv, __high2float(yv.h[1]), acco[3]);
            acco[4] = fmaf(wv, __low2float(yv.h[2]),  acco[4]);
            acco[5] = fmaf(wv, __high2float(yv.h[2]), acco[5]);
            acco[6] = fmaf(wv, __low2float(yv.h[3]),  acco[6]);
            acco[7] = fmaf(wv, __high2float(yv.h[3]), acco[7]);
        }
    }

    const int gy = by * TH + ty, gx = bx * TW + tx;
    float* op = out + ((size_t)(b * DIMC + g * GCH) * HH + gy) * WW + gx;
    #pragma unroll
    for (int cc = 0; cc < GCH; ++cc) op[cc * PLANE] = acco[cc];
}

// ---------- Fallback (known-good R2 fused kernel) ----------
#define CPAD 12
__global__ __launch_bounds__(256, 1)
void invol_fused_kernel(const float* __restrict__ x, const float* __restrict__ y,
                        const float* __restrict__ w1, const float* __restrict__ b1,
                        const float* __restrict__ w2, const float* __restrict__ b2,
                        float* __restrict__ out) {
    __shared__ float ytile[NPIX * CPAD];
    const int tid = threadIdx.x;
    const int tx = tid & 31, ty = tid >> 5;
    const int bx = blockIdx.x, by = blockIdx.y, bz = blockIdx.z;
    const int gx = bx * TW + tx, gy = by * TH + ty;

    float xv[DIMC];
    const float* xp = x + ((size_t)(bz * DIMC) * HH + gy) * WW + gx;
    #pragma unroll
    for (int c = 0; c < DIMC; ++c) xv[c] = xp[c * PLANE];

    float mid[CMID];
    #pragma unroll
    for (int m = 0; m < CMID; ++m) {
        float a = b1[m];
        const float4* w1r = reinterpret_cast<const float4*>(w1 + m * DIMC);
        #pragma unroll
        for (int cq = 0; cq < DIMC / 4; ++cq) {
            float4 wv = w1r[cq];
            a = fmaf(wv.x, xv[4*cq+0], a);
            a = fmaf(wv.y, xv[4*cq+1], a);
            a = fmaf(wv.z, xv[4*cq+2], a);
            a = fmaf(wv.w, xv[4*cq+3], a);
        }
        mid[m] = a;
    }

    for (int g = 0; g < NG; ++g) {
        __syncthreads();
        for (int i = tid; i < NPIX * GCH; i += 256) {
            int c = i / NPIX;
            int p = i - c * NPIX;
            int r = p / TPX;
            int col = p - r * TPX;
            int sy = by * TH + r - PADD;
            int sx = bx * TW + col - PADD;
            float v = 0.f;
            if (sy >= 0 && sy < HH && sx >= 0 && sx < WW)
                v = y[((size_t)(bz * DIMC + g * GCH + c) * HH + sy) * WW + sx];
            ytile[p * CPAD + c] = v;
        }
        __syncthreads();

        float wt[NTAP];
        const float*  b2g = b2 + g * NTAP;
        const float4* w2g = reinterpret_cast<const float4*>(w2 + g * NTAP * CMID);
        #pragma unroll
        for (int kk = 0; kk < NTAP; ++kk) {
            float a = b2g[kk];
            #pragma unroll
            for (int mq = 0; mq < CMID / 4; ++mq) {
                float4 wv = w2g[kk * (CMID / 4) + mq];
                a = fmaf(wv.x, mid[4*mq+0], a);
                a = fmaf(wv.y, mid[4*mq+1], a);
                a = fmaf(wv.z, mid[4*mq+2], a);
                a = fmaf(wv.w, mid[4*mq+3], a);
            }
            wt[kk] = a;
        }

        float acc[GCH];
        #pragma unroll
        for (int cc = 0; cc < GCH; ++cc) acc[cc] = 0.f;
        #pragma unroll
        for (int ky = 0; ky < KS; ++ky) {
            #pragma unroll
            for (int kx = 0; kx < KS; ++kx) {
                float wv = wt[ky * KS + kx];
                int pp = (ty + ky) * TPX + (tx + kx);
                const float4* yr = reinterpret_cast<const float4*>(&ytile[pp * CPAD]);
                float4 ya = yr[0];
                float4 yb = yr[1];
                acc[0] = fmaf(wv, ya.x, acc[0]);
                acc[1] = fmaf(wv, ya.y, acc[1]);
                acc[2] = fmaf(wv, ya.z, acc[2]);
                acc[3] = fmaf(wv, ya.w, acc[3]);
                acc[4] = fmaf(wv, yb.x, acc[4]);
                acc[5] = fmaf(wv, yb.y, acc[5]);
                acc[6] = fmaf(wv, yb.z, acc[6]);
                acc[7] = fmaf(wv, yb.w, acc[7]);
            }
        }

        float* op = out + ((size_t)(bz * DIMC + g * GCH) * HH + gy) * WW + gx;
        #pragma unroll
        for (int cc = 0; cc < GCH; ++cc) op[cc * PLANE] = acc[cc];
    }
}

extern "C" void kernel_launch(void* const* d_in, const int* in_sizes, int n_in,
                              void* d_out, int out_size, void* d_ws, size_t ws_size,
                              hipStream_t stream) {
    const float* x  = (const float*)d_in[0];
    const float* y  = (const float*)d_in[1];
    const float* w1 = (const float*)d_in[2];
    const float* b1 = (const float*)d_in[3];
    const float* w2 = (const float*)d_in[4];
    const float* b2 = (const float*)d_in[5];
    float* out = (float*)d_out;

    if (ws_size >= MIDWS_BYTES) {
        unsigned short* midws = (unsigned short*)d_ws;
        dim3 gridA(PLANE / 256, NB, 4);
        hipLaunchKernelGGL(midgen_kernel, gridA, dim3(256), 0, stream,
                           x, w1, b1, midws);
        dim3 gridB(WW / TW, HH / TH, NB * NG);
        hipLaunchKernelGGL(invol_mfma_kernel, gridB, dim3(256), 0, stream,
                           y, midws, w2, b2, out);
    } else {
        dim3 grid(WW / TW, HH / TH, NB);
        hipLaunchKernelGGL(invol_fused_kernel, grid, dim3(256), 0, stream,
                           x, y, w1, b1, w2, b2, out);
    }
}

// Round 7
// 42.549 us; speedup vs baseline: 6.6239x; 1.1374x over previous
//
#include <hip/hip_runtime.h>
#include <hip/hip_fp16.h>

#define DIMC 64
#define KS 7
#define NTAP 49
#define GCH 8
#define NG 8
#define CMID 32
#define PADD 3
#define HH 128
#define WW 128
#define PLANE (HH*WW)
#define TW 32
#define TH 8
#define TPX (TW+2*PADD)   // 38
#define TPY (TH+2*PADD)   // 14
#define NPIX (TPX*TPY)    // 532
#define NB 4
#define WTSTR 52          // padded wt row stride (f16 units)
#define NROW (NG*NTAP)    // 392
#define CPAD 12

// workspace layout (bytes)
#define WC_OFF 0                                   // 392*64 bf16 = 50176
#define BC_OFF 50176                               // 392 f32  = 1568
#define XT_OFF 52224                               // 4*16384*64 bf16 = 8388608
#define WS_NEED (XT_OFF + (size_t)NB * PLANE * DIMC * 2)

typedef __attribute__((ext_vector_type(8))) short short8;
typedef __attribute__((ext_vector_type(4))) float f32x4;
typedef __fp16 fp16x2 __attribute__((ext_vector_type(2)));

static __device__ inline unsigned short f2bs(float f) {   // fp32 -> bf16 (RNE)
    union { float f; unsigned u; } v; v.f = f;
    unsigned r = v.u + 0x7fff + ((v.u >> 16) & 1);
    return (unsigned short)(r >> 16);
}

static __device__ inline unsigned pkh(float a, float b) { // 2x fp32 -> packed f16 (RTZ)
    union { fp16x2 h; unsigned u; } c;
    c.h = __builtin_amdgcn_cvt_pkrtz(a, b);
    return c.u;
}

// ---------- P1: Wc = W2 @ W1 (bf16), bc = W2 @ b1 + b2 (f32) ----------
__global__ __launch_bounds__(256)
void prep_weights(const float* __restrict__ w1, const float* __restrict__ b1,
                  const float* __restrict__ w2, const float* __restrict__ b2,
                  unsigned short* __restrict__ wc, float* __restrict__ bc) {
    int idx = blockIdx.x * 256 + threadIdx.x;
    if (idx >= NROW * 16) return;
    int row = idx >> 4;            // 0..391
    int c0 = (idx & 15) * 4;
    const float* w2r = w2 + row * CMID;
    float a0 = 0.f, a1 = 0.f, a2 = 0.f, a3 = 0.f;
    #pragma unroll
    for (int m = 0; m < CMID; ++m) {
        float wv = w2r[m];
        const float* w1r = w1 + m * DIMC + c0;
        a0 = fmaf(wv, w1r[0], a0);
        a1 = fmaf(wv, w1r[1], a1);
        a2 = fmaf(wv, w1r[2], a2);
        a3 = fmaf(wv, w1r[3], a3);
    }
    *reinterpret_cast<uint2*>(wc + row * DIMC + c0) =
        make_uint2(((unsigned)f2bs(a1) << 16) | f2bs(a0),
                   ((unsigned)f2bs(a3) << 16) | f2bs(a2));
    if ((idx & 15) == 0) {
        float s = b2[row];
        #pragma unroll
        for (int m = 0; m < CMID; ++m) s = fmaf(w2r[m], b1[m], s);
        bc[row] = s;
    }
}

// ---------- P2: xT[b][kq][px][8c] bf16 (pure transpose/cast) ----------
__global__ __launch_bounds__(256)
void prep_xt(const float* __restrict__ x, unsigned short* __restrict__ xt) {
    const int px = blockIdx.x * 256 + threadIdx.x;
    const int b = blockIdx.y;
    const int h = blockIdx.z;          // c half: channels h*32 .. h*32+31
    const float* xp = x + (size_t)b * DIMC * PLANE + (size_t)h * 32 * PLANE + px;
    #pragma unroll
    for (int q = 0; q < 4; ++q) {      // kq = h*4+q, 8 channels each
        unsigned pk[4];
        #pragma unroll
        for (int j = 0; j < 4; ++j) {
            float v0 = xp[(size_t)(q * 8 + 2 * j) * PLANE];
            float v1 = xp[(size_t)(q * 8 + 2 * j + 1) * PLANE];
            pk[j] = ((unsigned)f2bs(v1) << 16) | f2bs(v0);
        }
        *reinterpret_cast<uint4*>(xt + (((size_t)b * 8 + h * 4 + q) * PLANE + px) * 8) =
            make_uint4(pk[0], pk[1], pk[2], pk[3]);
    }
}

// ---------- Kernel B: wt = Wc@xT + bc via MFMA, then f16 involution ----------
__global__ __launch_bounds__(256, 4)
void invol_mfma2_kernel(const float* __restrict__ y,
                        const unsigned short* __restrict__ xt,
                        const unsigned short* __restrict__ wc,
                        const float* __restrict__ bc,
                        float* __restrict__ out) {
    __shared__ __half ytile[NPIX * GCH];     // 8512 B
    __shared__ __half wtl[256 * WTSTR];      // 26624 B

    const int tid = threadIdx.x;
    const int l = tid & 63, w = tid >> 6;
    const int bx = blockIdx.x, by = blockIdx.y;
    const int b = blockIdx.z >> 3, g = blockIdx.z & 7;

    // ---- stage y halo as f16 [px][8ch] ----
    #pragma unroll
    for (int k = 0; k < 5; ++k) {
        int i = tid + k * 256;
        if (i < NPIX * 2) {
            int q  = i / NPIX;              // channel quad 0/1
            int px = i - q * NPIX;
            int c0 = q * 4;
            int r = px / TPX, col = px - r * TPX;
            int sy = by * TH + r - PADD, sx = bx * TW + col - PADD;
            bool ok = (sy >= 0 && sy < HH && sx >= 0 && sx < WW);
            const float* yp = y + ((size_t)(b * DIMC + g * GCH + c0) * HH + sy) * WW + sx;
            float v0 = ok ? yp[0] : 0.f;
            float v1 = ok ? yp[PLANE] : 0.f;
            float v2 = ok ? yp[2 * PLANE] : 0.f;
            float v3 = ok ? yp[3 * PLANE] : 0.f;
            *reinterpret_cast<uint2*>(&ytile[px * GCH + c0]) =
                make_uint2(pkh(v0, v1), pkh(v2, v3));
        }
    }

    // ---- GEMM: wt[64pad][256px] = Wc[g] (49x64) @ xT (64x256), K=64 ----
    const int fr = l & 15, fk = l >> 4;
    f32x4 acc[4][4];
    #pragma unroll
    for (int mt = 0; mt < 4; ++mt)
        #pragma unroll
        for (int nt = 0; nt < 4; ++nt)
            acc[mt][nt] = f32x4{0.f, 0.f, 0.f, 0.f};

    int gpix[4];
    #pragma unroll
    for (int nt = 0; nt < 4; ++nt) {
        int lp = w * 64 + nt * 16 + fr;
        gpix[nt] = (by * TH + (lp >> 5)) * WW + bx * TW + (lp & 31);
    }

    #pragma unroll
    for (int kp = 0; kp < 2; ++kp) {
        short8 af[4];
        #pragma unroll
        for (int mt = 0; mt < 4; ++mt) {
            int row = mt * 16 + fr;
            union { uint4 u; short8 s; } cv;
            cv.u = make_uint4(0u, 0u, 0u, 0u);
            if (row < NTAP)
                cv.u = *reinterpret_cast<const uint4*>(
                    wc + ((size_t)(g * NTAP + row)) * DIMC + kp * 32 + fk * 8);
            af[mt] = cv.s;
        }
        short8 bf[4];
        #pragma unroll
        for (int nt = 0; nt < 4; ++nt) {
            union { uint4 u; short8 s; } cv;
            cv.u = *reinterpret_cast<const uint4*>(
                xt + (((size_t)b * 8 + kp * 4 + fk) * PLANE + gpix[nt]) * 8);
            bf[nt] = cv.s;
        }
        #pragma unroll
        for (int mt = 0; mt < 4; ++mt)
            #pragma unroll
            for (int nt = 0; nt < 4; ++nt)
                acc[mt][nt] = __builtin_amdgcn_mfma_f32_16x16x32_bf16(
                    af[mt], bf[nt], acc[mt][nt], 0, 0, 0);
    }

    // ---- bias + C -> wtl (f16). C layout: col=lane&15, row=(lane>>4)*4+reg ----
    const int r0 = fk * 4;
    #pragma unroll
    for (int mt = 0; mt < 4; ++mt) {
        if (mt < 3 || r0 == 0) {
            int rb = mt * 16 + r0;
            float bb[4];
            #pragma unroll
            for (int j = 0; j < 4; ++j)
                bb[j] = (rb + j < NTAP) ? bc[g * NTAP + rb + j] : 0.f;
            #pragma unroll
            for (int nt = 0; nt < 4; ++nt) {
                int lp = w * 64 + nt * 16 + fr;
                *reinterpret_cast<uint2*>(&wtl[lp * WTSTR + rb]) =
                    make_uint2(pkh(acc[mt][nt][0] + bb[0], acc[mt][nt][1] + bb[1]),
                               pkh(acc[mt][nt][2] + bb[2], acc[mt][nt][3] + bb[3]));
            }
        }
    }

    __syncthreads();

    // ---- read own wt row (packed halves, 26 regs) ----
    __half2 wth[26];
    const __half2* wrow = reinterpret_cast<const __half2*>(&wtl[tid * WTSTR]);
    #pragma unroll
    for (int q = 0; q < 26; ++q) wth[q] = wrow[q];

    // ---- involution: 49 taps x 8 f16 channels ----
    const int tx = tid & 31, ty = tid >> 5;
    float acco[GCH];
    #pragma unroll
    for (int cc = 0; cc < GCH; ++cc) acco[cc] = 0.f;
    #pragma unroll
    for (int ky = 0; ky < KS; ++ky) {
        #pragma unroll
        for (int kx = 0; kx < KS; ++kx) {
            const int kk = ky * KS + kx;
            float wv = (kk & 1) ? __high2float(wth[kk >> 1]) : __low2float(wth[kk >> 1]);
            int pp = (ty + ky) * TPX + (tx + kx);
            union { uint4 u; __half2 h[4]; } yv;
            yv.u = *reinterpret_cast<const uint4*>(&ytile[pp * GCH]);
            acco[0] = fmaf(wv, __low2float(yv.h[0]),  acco[0]);
            acco[1] = fmaf(wv, __high2float(yv.h[0]), acco[1]);
            acco[2] = fmaf(wv, __low2float(yv.h[1]),  acco[2]);
            acco[3] = fmaf(wv, __high2float(yv.h[1]), acco[3]);
            acco[4] = fmaf(wv, __low2float(yv.h[2]),  acco[4]);
            acco[5] = fmaf(wv, __high2float(yv.h[2]), acco[5]);
            acco[6] = fmaf(wv, __low2float(yv.h[3]),  acco[6]);
            acco[7] = fmaf(wv, __high2float(yv.h[3]), acco[7]);
        }
    }

    const int gy = by * TH + ty, gx = bx * TW + tx;
    float* op = out + ((size_t)(b * DIMC + g * GCH) * HH + gy) * WW + gx;
    #pragma unroll
    for (int cc = 0; cc < GCH; ++cc) op[cc * PLANE] = acco[cc];
}

// ---------- Fallback (known-good R2 fused kernel) ----------
__global__ __launch_bounds__(256, 1)
void invol_fused_kernel(const float* __restrict__ x, const float* __restrict__ y,
                        const float* __restrict__ w1, const float* __restrict__ b1,
                        const float* __restrict__ w2, const float* __restrict__ b2,
                        float* __restrict__ out) {
    __shared__ float ytile[NPIX * CPAD];
    const int tid = threadIdx.x;
    const int tx = tid & 31, ty = tid >> 5;
    const int bx = blockIdx.x, by = blockIdx.y, bz = blockIdx.z;
    const int gx = bx * TW + tx, gy = by * TH + ty;

    float xv[DIMC];
    const float* xp = x + ((size_t)(bz * DIMC) * HH + gy) * WW + gx;
    #pragma unroll
    for (int c = 0; c < DIMC; ++c) xv[c] = xp[c * PLANE];

    float mid[CMID];
    #pragma unroll
    for (int m = 0; m < CMID; ++m) {
        float a = b1[m];
        const float4* w1r = reinterpret_cast<const float4*>(w1 + m * DIMC);
        #pragma unroll
        for (int cq = 0; cq < DIMC / 4; ++cq) {
            float4 wv = w1r[cq];
            a = fmaf(wv.x, xv[4*cq+0], a);
            a = fmaf(wv.y, xv[4*cq+1], a);
            a = fmaf(wv.z, xv[4*cq+2], a);
            a = fmaf(wv.w, xv[4*cq+3], a);
        }
        mid[m] = a;
    }

    for (int g = 0; g < NG; ++g) {
        __syncthreads();
        for (int i = tid; i < NPIX * GCH; i += 256) {
            int c = i / NPIX;
            int p = i - c * NPIX;
            int r = p / TPX;
            int col = p - r * TPX;
            int sy = by * TH + r - PADD;
            int sx = bx * TW + col - PADD;
            float v = 0.f;
            if (sy >= 0 && sy < HH && sx >= 0 && sx < WW)
                v = y[((size_t)(bz * DIMC + g * GCH + c) * HH + sy) * WW + sx];
            ytile[p * CPAD + c] = v;
        }
        __syncthreads();

        float wt[NTAP];
        const float*  b2g = b2 + g * NTAP;
        const float4* w2g = reinterpret_cast<const float4*>(w2 + g * NTAP * CMID);
        #pragma unroll
        for (int kk = 0; kk < NTAP; ++kk) {
            float a = b2g[kk];
            #pragma unroll
            for (int mq = 0; mq < CMID / 4; ++mq) {
                float4 wv = w2g[kk * (CMID / 4) + mq];
                a = fmaf(wv.x, mid[4*mq+0], a);
                a = fmaf(wv.y, mid[4*mq+1], a);
                a = fmaf(wv.z, mid[4*mq+2], a);
                a = fmaf(wv.w, mid[4*mq+3], a);
            }
            wt[kk] = a;
        }

        float acc[GCH];
        #pragma unroll
        for (int cc = 0; cc < GCH; ++cc) acc[cc] = 0.f;
        #pragma unroll
        for (int ky = 0; ky < KS; ++ky) {
            #pragma unroll
            for (int kx = 0; kx < KS; ++kx) {
                float wv = wt[ky * KS + kx];
                int pp = (ty + ky) * TPX + (tx + kx);
                const float4* yr = reinterpret_cast<const float4*>(&ytile[pp * CPAD]);
                float4 ya = yr[0];
                float4 yb = yr[1];
                acc[0] = fmaf(wv, ya.x, acc[0]);
                acc[1] = fmaf(wv, ya.y, acc[1]);
                acc[2] = fmaf(wv, ya.z, acc[2]);
                acc[3] = fmaf(wv, ya.w, acc[3]);
                acc[4] = fmaf(wv, yb.x, acc[4]);
                acc[5] = fmaf(wv, yb.y, acc[5]);
                acc[6] = fmaf(wv, yb.z, acc[6]);
                acc[7] = fmaf(wv, yb.w, acc[7]);
            }
        }

        float* op = out + ((size_t)(bz * DIMC + g * GCH) * HH + gy) * WW + gx;
        #pragma unroll
        for (int cc = 0; cc < GCH; ++cc) op[cc * PLANE] = acc[cc];
    }
}

extern "C" void kernel_launch(void* const* d_in, const int* in_sizes, int n_in,
                              void* d_out, int out_size, void* d_ws, size_t ws_size,
                              hipStream_t stream) {
    const float* x  = (const float*)d_in[0];
    const float* y  = (const float*)d_in[1];
    const float* w1 = (const float*)d_in[2];
    const float* b1 = (const float*)d_in[3];
    const float* w2 = (const float*)d_in[4];
    const float* b2 = (const float*)d_in[5];
    float* out = (float*)d_out;

    if (ws_size >= WS_NEED) {
        char* ws = (char*)d_ws;
        unsigned short* wcp = (unsigned short*)(ws + WC_OFF);
        float*          bcp = (float*)(ws + BC_OFF);
        unsigned short* xtp = (unsigned short*)(ws + XT_OFF);

        hipLaunchKernelGGL(prep_weights, dim3((NROW * 16 + 255) / 256), dim3(256), 0, stream,
                           w1, b1, w2, b2, wcp, bcp);
        hipLaunchKernelGGL(prep_xt, dim3(PLANE / 256, NB, 2), dim3(256), 0, stream,
                           x, xtp);
        hipLaunchKernelGGL(invol_mfma2_kernel, dim3(WW / TW, HH / TH, NB * NG), dim3(256), 0, stream,
                           y, xtp, wcp, bcp, out);
    } else {
        dim3 grid(WW / TW, HH / TH, NB);
        hipLaunchKernelGGL(invol_fused_kernel, grid, dim3(256), 0, stream,
                           x, y, w1, b1, w2, b2, out);
    }
}

// Round 8
// 38.961 us; speedup vs baseline: 7.2339x; 1.0921x over previous
//
#include <hip/hip_runtime.h>
#include <hip/hip_fp16.h>

#define DIMC 64
#define KS 7
#define NTAP 49
#define GCH 8
#define NG 8
#define CMID 32
#define PADD 3
#define HH 128
#define WW 128
#define PLANE (HH*WW)
#define TW 32
#define TH 8
#define TPX (TW+2*PADD)   // 38
#define TPY (TH+2*PADD)   // 14
#define NPIX (TPX*TPY)    // 532
#define NB 4
#define WTSTR 54          // padded wt row stride (f16 units), 27 dwords (odd)
#define CPAD 12

// workspace layout (bytes); Wc/bc padded to 64 rows per group (rows 49..63 = 0)
#define WC_OFF 0                                   // 8*64*64 bf16 = 65536
#define BC_OFF 65536                               // 512 f32 = 2048
#define XT_OFF 67584                               // 4*16384*64 bf16 = 8388608
#define WS_NEED (XT_OFF + (size_t)NB * PLANE * DIMC * 2)

typedef __attribute__((ext_vector_type(8))) short short8;
typedef __attribute__((ext_vector_type(4))) float f32x4;
typedef __fp16 fp16x2 __attribute__((ext_vector_type(2)));

static __device__ inline unsigned short f2bs(float f) {   // fp32 -> bf16 (RNE)
    union { float f; unsigned u; } v; v.f = f;
    unsigned r = v.u + 0x7fff + ((v.u >> 16) & 1);
    return (unsigned short)(r >> 16);
}

static __device__ inline unsigned pkh(float a, float b) { // 2x fp32 -> packed f16 (RTZ)
    union { fp16x2 h; unsigned u; } c;
    c.h = __builtin_amdgcn_cvt_pkrtz(a, b);
    return c.u;
}

// ---------- P: merged prep. blocks [0,512): xT transpose/cast; [512,544): Wc/bc ----------
__global__ __launch_bounds__(256)
void prep_all(const float* __restrict__ x,
              const float* __restrict__ w1, const float* __restrict__ b1,
              const float* __restrict__ w2, const float* __restrict__ b2,
              unsigned short* __restrict__ wc, float* __restrict__ bc,
              unsigned short* __restrict__ xt) {
    const int bid = blockIdx.x;
    if (bid < 512) {
        // xT[b][kq][px][8c] bf16, kq = h*4+q
        const int pxblk = bid & 63, rest = bid >> 6;
        const int b = rest & 3, h = rest >> 2;
        const int px = pxblk * 256 + threadIdx.x;
        const float* xp = x + (size_t)b * DIMC * PLANE + (size_t)h * 32 * PLANE + px;
        #pragma unroll
        for (int q = 0; q < 4; ++q) {
            unsigned pk[4];
            #pragma unroll
            for (int j = 0; j < 4; ++j) {
                float v0 = xp[(size_t)(q * 8 + 2 * j) * PLANE];
                float v1 = xp[(size_t)(q * 8 + 2 * j + 1) * PLANE];
                pk[j] = ((unsigned)f2bs(v1) << 16) | f2bs(v0);
            }
            *reinterpret_cast<uint4*>(xt + (((size_t)b * 8 + h * 4 + q) * PLANE + px) * 8) =
                make_uint4(pk[0], pk[1], pk[2], pk[3]);
        }
    } else {
        // Wc[g][r64][DIMC] = W2@W1 (bf16, pad rows zero); bc[g][r64] = W2@b1+b2
        const int idx = (bid - 512) * 256 + threadIdx.x;   // 0..8191
        const int row64 = idx >> 4;                        // 0..511
        const int c0 = (idx & 15) * 4;
        const int g = row64 >> 6, r = row64 & 63;
        float a0 = 0.f, a1 = 0.f, a2 = 0.f, a3 = 0.f, bv = 0.f;
        if (r < NTAP) {
            const float* w2r = w2 + (g * NTAP + r) * CMID;
            #pragma unroll
            for (int m = 0; m < CMID; ++m) {
                float wv = w2r[m];
                const float* w1r = w1 + m * DIMC + c0;
                a0 = fmaf(wv, w1r[0], a0);
                a1 = fmaf(wv, w1r[1], a1);
                a2 = fmaf(wv, w1r[2], a2);
                a3 = fmaf(wv, w1r[3], a3);
            }
            if (c0 == 0) {
                bv = b2[g * NTAP + r];
                #pragma unroll
                for (int m = 0; m < CMID; ++m) bv = fmaf(w2r[m], b1[m], bv);
            }
        }
        *reinterpret_cast<uint2*>(wc + row64 * DIMC + c0) =
            make_uint2(((unsigned)f2bs(a1) << 16) | f2bs(a0),
                       ((unsigned)f2bs(a3) << 16) | f2bs(a2));
        if ((idx & 15) == 0) bc[row64] = bv;
    }
}

// ---------- Kernel B: wt = Wc@xT + bc via MFMA, then packed-f16 involution ----------
__global__ __launch_bounds__(256, 4)
void invol_mfma3_kernel(const float* __restrict__ y,
                        const unsigned short* __restrict__ xt,
                        const unsigned short* __restrict__ wc,
                        const float* __restrict__ bc,
                        float* __restrict__ out) {
    __shared__ __half ytile[NPIX * GCH];     // 8512 B
    __shared__ __half wtl[256 * WTSTR];      // 27648 B

    const int tid = threadIdx.x;
    const int l = tid & 63, w = tid >> 6;
    const int bx = blockIdx.x, by = blockIdx.y;
    const int b = blockIdx.z >> 3, g = blockIdx.z & 7;

    // ---- stage y halo as f16 [px][8ch] ----
    #pragma unroll
    for (int k = 0; k < 5; ++k) {
        int i = tid + k * 256;
        if (i < NPIX * 2) {
            int q  = i / NPIX;              // channel quad 0/1
            int px = i - q * NPIX;
            int c0 = q * 4;
            int r = px / TPX, col = px - r * TPX;
            int sy = by * TH + r - PADD, sx = bx * TW + col - PADD;
            bool ok = (sy >= 0 && sy < HH && sx >= 0 && sx < WW);
            const float* yp = y + ((size_t)(b * DIMC + g * GCH + c0) * HH + sy) * WW + sx;
            float v0 = ok ? yp[0] : 0.f;
            float v1 = ok ? yp[PLANE] : 0.f;
            float v2 = ok ? yp[2 * PLANE] : 0.f;
            float v3 = ok ? yp[3 * PLANE] : 0.f;
            *reinterpret_cast<uint2*>(&ytile[px * GCH + c0]) =
                make_uint2(pkh(v0, v1), pkh(v2, v3));
        }
    }

    // ---- GEMM: wt[64pad][256px] = Wc[g] (64x64) @ xT (64x256), K=64 ----
    const int fr = l & 15, fk = l >> 4;
    f32x4 acc[4][4];
    #pragma unroll
    for (int mt = 0; mt < 4; ++mt)
        #pragma unroll
        for (int nt = 0; nt < 4; ++nt)
            acc[mt][nt] = f32x4{0.f, 0.f, 0.f, 0.f};

    int gpix[4];
    #pragma unroll
    for (int nt = 0; nt < 4; ++nt) {
        int lp = w * 64 + nt * 16 + fr;
        gpix[nt] = (by * TH + (lp >> 5)) * WW + bx * TW + (lp & 31);
    }

    #pragma unroll
    for (int kp = 0; kp < 2; ++kp) {
        short8 af[4];
        #pragma unroll
        for (int mt = 0; mt < 4; ++mt) {
            union { uint4 u; short8 s; } cv;
            cv.u = *reinterpret_cast<const uint4*>(
                wc + ((size_t)(g * 64 + mt * 16 + fr)) * DIMC + kp * 32 + fk * 8);
            af[mt] = cv.s;
        }
        short8 bf[4];
        #pragma unroll
        for (int nt = 0; nt < 4; ++nt) {
            union { uint4 u; short8 s; } cv;
            cv.u = *reinterpret_cast<const uint4*>(
                xt + (((size_t)b * 8 + kp * 4 + fk) * PLANE + gpix[nt]) * 8);
            bf[nt] = cv.s;
        }
        #pragma unroll
        for (int mt = 0; mt < 4; ++mt)
            #pragma unroll
            for (int nt = 0; nt < 4; ++nt)
                acc[mt][nt] = __builtin_amdgcn_mfma_f32_16x16x32_bf16(
                    af[mt], bf[nt], acc[mt][nt], 0, 0, 0);
    }

    // ---- bias + C -> wtl (f16). C layout: col=lane&15, row=(lane>>4)*4+reg ----
    const int r0 = fk * 4;
    #pragma unroll
    for (int mt = 0; mt < 4; ++mt) {
        if (mt < 3 || r0 == 0) {           // keep writes within taps 0..51
            int rb = mt * 16 + r0;
            float bb0 = bc[g * 64 + rb + 0], bb1 = bc[g * 64 + rb + 1];
            float bb2 = bc[g * 64 + rb + 2], bb3 = bc[g * 64 + rb + 3];
            #pragma unroll
            for (int nt = 0; nt < 4; ++nt) {
                int lp = w * 64 + nt * 16 + fr;
                *reinterpret_cast<uint2*>(&wtl[lp * WTSTR + rb]) =
                    make_uint2(pkh(acc[mt][nt][0] + bb0, acc[mt][nt][1] + bb1),
                               pkh(acc[mt][nt][2] + bb2, acc[mt][nt][3] + bb3));
            }
        }
    }

    __syncthreads();

    // ---- read own wt row (packed halves) ----
    __half2 wth[26];
    const __half2* wrow = reinterpret_cast<const __half2*>(&wtl[tid * WTSTR]);
    #pragma unroll
    for (int q = 0; q < 26; ++q) wth[q] = wrow[q];

    // ---- involution: 49 taps x 8 f16 channels, packed v_pk_fma_f16 ----
    const int tx = tid & 31, ty = tid >> 5;
    __half2 acch[4];
    #pragma unroll
    for (int cc = 0; cc < 4; ++cc) acch[cc] = __float2half2_rn(0.f);
    #pragma unroll
    for (int ky = 0; ky < KS; ++ky) {
        #pragma unroll
        for (int kx = 0; kx < KS; ++kx) {
            const int kk = ky * KS + kx;
            __half wh = (kk & 1) ? __high2half(wth[kk >> 1]) : __low2half(wth[kk >> 1]);
            __half2 wv2 = __half2half2(wh);
            int pp = (ty + ky) * TPX + (tx + kx);
            union { uint4 u; __half2 h[4]; } yv;
            yv.u = *reinterpret_cast<const uint4*>(&ytile[pp * GCH]);
            acch[0] = __hfma2(wv2, yv.h[0], acch[0]);
            acch[1] = __hfma2(wv2, yv.h[1], acch[1]);
            acch[2] = __hfma2(wv2, yv.h[2], acch[2]);
            acch[3] = __hfma2(wv2, yv.h[3], acch[3]);
        }
    }

    const int gy = by * TH + ty, gx = bx * TW + tx;
    float* op = out + ((size_t)(b * DIMC + g * GCH) * HH + gy) * WW + gx;
    #pragma unroll
    for (int cc = 0; cc < 4; ++cc) {
        float2 f = __half22float2(acch[cc]);
        op[(2 * cc) * PLANE]     = f.x;
        op[(2 * cc + 1) * PLANE] = f.y;
    }
}

// ---------- Fallback (known-good R2 fused kernel) ----------
__global__ __launch_bounds__(256, 1)
void invol_fused_kernel(const float* __restrict__ x, const float* __restrict__ y,
                        const float* __restrict__ w1, const float* __restrict__ b1,
                        const float* __restrict__ w2, const float* __restrict__ b2,
                        float* __restrict__ out) {
    __shared__ float ytile[NPIX * CPAD];
    const int tid = threadIdx.x;
    const int tx = tid & 31, ty = tid >> 5;
    const int bx = blockIdx.x, by = blockIdx.y, bz = blockIdx.z;
    const int gx = bx * TW + tx, gy = by * TH + ty;

    float xv[DIMC];
    const float* xp = x + ((size_t)(bz * DIMC) * HH + gy) * WW + gx;
    #pragma unroll
    for (int c = 0; c < DIMC; ++c) xv[c] = xp[c * PLANE];

    float mid[CMID];
    #pragma unroll
    for (int m = 0; m < CMID; ++m) {
        float a = b1[m];
        const float4* w1r = reinterpret_cast<const float4*>(w1 + m * DIMC);
        #pragma unroll
        for (int cq = 0; cq < DIMC / 4; ++cq) {
            float4 wv = w1r[cq];
            a = fmaf(wv.x, xv[4*cq+0], a);
            a = fmaf(wv.y, xv[4*cq+1], a);
            a = fmaf(wv.z, xv[4*cq+2], a);
            a = fmaf(wv.w, xv[4*cq+3], a);
        }
        mid[m] = a;
    }

    for (int g = 0; g < NG; ++g) {
        __syncthreads();
        for (int i = tid; i < NPIX * GCH; i += 256) {
            int c = i / NPIX;
            int p = i - c * NPIX;
            int r = p / TPX;
            int col = p - r * TPX;
            int sy = by * TH + r - PADD;
            int sx = bx * TW + col - PADD;
            float v = 0.f;
            if (sy >= 0 && sy < HH && sx >= 0 && sx < WW)
                v = y[((size_t)(bz * DIMC + g * GCH + c) * HH + sy) * WW + sx];
            ytile[p * CPAD + c] = v;
        }
        __syncthreads();

        float wt[NTAP];
        const float*  b2g = b2 + g * NTAP;
        const float4* w2g = reinterpret_cast<const float4*>(w2 + g * NTAP * CMID);
        #pragma unroll
        for (int kk = 0; kk < NTAP; ++kk) {
            float a = b2g[kk];
            #pragma unroll
            for (int mq = 0; mq < CMID / 4; ++mq) {
                float4 wv = w2g[kk * (CMID / 4) + mq];
                a = fmaf(wv.x, mid[4*mq+0], a);
                a = fmaf(wv.y, mid[4*mq+1], a);
                a = fmaf(wv.z, mid[4*mq+2], a);
                a = fmaf(wv.w, mid[4*mq+3], a);
            }
            wt[kk] = a;
        }

        float acc[GCH];
        #pragma unroll
        for (int cc = 0; cc < GCH; ++cc) acc[cc] = 0.f;
        #pragma unroll
        for (int ky = 0; ky < KS; ++ky) {
            #pragma unroll
            for (int kx = 0; kx < KS; ++kx) {
                float wv = wt[ky * KS + kx];
                int pp = (ty + ky) * TPX + (tx + kx);
                const float4* yr = reinterpret_cast<const float4*>(&ytile[pp * CPAD]);
                float4 ya = yr[0];
                float4 yb = yr[1];
                acc[0] = fmaf(wv, ya.x, acc[0]);
                acc[1] = fmaf(wv, ya.y, acc[1]);
                acc[2] = fmaf(wv, ya.z, acc[2]);
                acc[3] = fmaf(wv, ya.w, acc[3]);
                acc[4] = fmaf(wv, yb.x, acc[4]);
                acc[5] = fmaf(wv, yb.y, acc[5]);
                acc[6] = fmaf(wv, yb.z, acc[6]);
                acc[7] = fmaf(wv, yb.w, acc[7]);
            }
        }

        float* op = out + ((size_t)(bz * DIMC + g * GCH) * HH + gy) * WW + gx;
        #pragma unroll
        for (int cc = 0; cc < GCH; ++cc) op[cc * PLANE] = acc[cc];
    }
}

extern "C" void kernel_launch(void* const* d_in, const int* in_sizes, int n_in,
                              void* d_out, int out_size, void* d_ws, size_t ws_size,
                              hipStream_t stream) {
    const float* x  = (const float*)d_in[0];
    const float* y  = (const float*)d_in[1];
    const float* w1 = (const float*)d_in[2];
    const float* b1 = (const float*)d_in[3];
    const float* w2 = (const float*)d_in[4];
    const float* b2 = (const float*)d_in[5];
    float* out = (float*)d_out;

    if (ws_size >= WS_NEED) {
        char* ws = (char*)d_ws;
        unsigned short* wcp = (unsigned short*)(ws + WC_OFF);
        float*          bcp = (float*)(ws + BC_OFF);
        unsigned short* xtp = (unsigned short*)(ws + XT_OFF);

        hipLaunchKernelGGL(prep_all, dim3(512 + 32), dim3(256), 0, stream,
                           x, w1, b1, w2, b2, wcp, bcp, xtp);
        hipLaunchKernelGGL(invol_mfma3_kernel, dim3(WW / TW, HH / TH, NB * NG), dim3(256), 0, stream,
                           y, xtp, wcp, bcp, out);
    } else {
        dim3 grid(WW / TW, HH / TH, NB);
        hipLaunchKernelGGL(invol_fused_kernel, grid, dim3(256), 0, stream,
                           x, y, w1, b1, w2, b2, out);
    }
}

// Round 9
// 34.472 us; speedup vs baseline: 8.1759x; 1.1302x over previous
//
#include <hip/hip_runtime.h>
#include <hip/hip_fp16.h>

#define DIMC 64
#define KS 7
#define NTAP 49
#define GCH 8
#define NG 8
#define CMID 32
#define PADD 3
#define HH 128
#define WW 128
#define PLANE (HH*WW)
#define TW 32
#define TH 8
#define TPX (TW+2*PADD)   // 38
#define TPY (TH+2*PADD)   // 14
#define NPIX (TPX*TPY)    // 532
#define NB 4
#define WTSTR 36          // super-chunk row stride (halves): 18 dwords, b64-aligned, 2-way banks
#define CPAD 12

// workspace layout (bytes); Wc/bc padded to 64 rows per group (rows 49..63 = 0)
#define WC_OFF 0                                   // 8*64*64 bf16 = 65536
#define BC_OFF 65536                               // 512 f32 = 2048
#define XT_OFF 67584                               // 4*16384*64 bf16 = 8388608
#define WS_NEED (XT_OFF + (size_t)NB * PLANE * DIMC * 2)

typedef __attribute__((ext_vector_type(8))) short short8;
typedef __attribute__((ext_vector_type(4))) float f32x4;
typedef __fp16 fp16x2 __attribute__((ext_vector_type(2)));

static __device__ inline unsigned short f2bs(float f) {   // fp32 -> bf16 (RNE)
    union { float f; unsigned u; } v; v.f = f;
    unsigned r = v.u + 0x7fff + ((v.u >> 16) & 1);
    return (unsigned short)(r >> 16);
}

static __device__ inline unsigned pkh(float a, float b) { // 2x fp32 -> packed f16 (RTZ)
    union { fp16x2 h; unsigned u; } c;
    c.h = __builtin_amdgcn_cvt_pkrtz(a, b);
    return c.u;
}

// ---------- P: merged prep. blocks [0,512): xT transpose/cast; [512,544): Wc/bc ----------
__global__ __launch_bounds__(256)
void prep_all(const float* __restrict__ x,
              const float* __restrict__ w1, const float* __restrict__ b1,
              const float* __restrict__ w2, const float* __restrict__ b2,
              unsigned short* __restrict__ wc, float* __restrict__ bc,
              unsigned short* __restrict__ xt) {
    const int bid = blockIdx.x;
    if (bid < 512) {
        const int pxblk = bid & 63, rest = bid >> 6;
        const int b = rest & 3, h = rest >> 2;
        const int px = pxblk * 256 + threadIdx.x;
        const float* xp = x + (size_t)b * DIMC * PLANE + (size_t)h * 32 * PLANE + px;
        #pragma unroll
        for (int q = 0; q < 4; ++q) {
            unsigned pk[4];
            #pragma unroll
            for (int j = 0; j < 4; ++j) {
                float v0 = xp[(size_t)(q * 8 + 2 * j) * PLANE];
                float v1 = xp[(size_t)(q * 8 + 2 * j + 1) * PLANE];
                pk[j] = ((unsigned)f2bs(v1) << 16) | f2bs(v0);
            }
            *reinterpret_cast<uint4*>(xt + (((size_t)b * 8 + h * 4 + q) * PLANE + px) * 8) =
                make_uint4(pk[0], pk[1], pk[2], pk[3]);
        }
    } else {
        const int idx = (bid - 512) * 256 + threadIdx.x;   // 0..8191
        const int row64 = idx >> 4;                        // 0..511
        const int c0 = (idx & 15) * 4;
        const int g = row64 >> 6, r = row64 & 63;
        float a0 = 0.f, a1 = 0.f, a2 = 0.f, a3 = 0.f, bv = 0.f;
        if (r < NTAP) {
            const float* w2r = w2 + (g * NTAP + r) * CMID;
            #pragma unroll
            for (int m = 0; m < CMID; ++m) {
                float wv = w2r[m];
                const float* w1r = w1 + m * DIMC + c0;
                a0 = fmaf(wv, w1r[0], a0);
                a1 = fmaf(wv, w1r[1], a1);
                a2 = fmaf(wv, w1r[2], a2);
                a3 = fmaf(wv, w1r[3], a3);
            }
            if (c0 == 0) {
                bv = b2[g * NTAP + r];
                #pragma unroll
                for (int m = 0; m < CMID; ++m) bv = fmaf(w2r[m], b1[m], bv);
            }
        }
        *reinterpret_cast<uint2*>(wc + row64 * DIMC + c0) =
            make_uint2(((unsigned)f2bs(a1) << 16) | f2bs(a0),
                       ((unsigned)f2bs(a3) << 16) | f2bs(a2));
        if ((idx & 15) == 0) bc[row64] = bv;
    }
}

// ---------- Kernel B: chunked MFMA wt-GEMM interleaved with packed-f16 involution ----------
__global__ __launch_bounds__(256, 5)
void invol_mfma4_kernel(const float* __restrict__ y,
                        const unsigned short* __restrict__ xt,
                        const unsigned short* __restrict__ wc,
                        const float* __restrict__ bc,
                        float* __restrict__ out) {
    __shared__ __half ytile[NPIX * GCH];     // 8512 B
    __shared__ __half wtl[256 * WTSTR];      // 18432 B (32-tap super-chunk, reused 2x)

    const int tid = threadIdx.x;
    const int l = tid & 63, w = tid >> 6;
    const int fr = l & 15, fk = l >> 4;
    const int bx = blockIdx.x, by = blockIdx.y;
    const int b = blockIdx.z >> 3, g = blockIdx.z & 7;
    const int tx = tid & 31, ty = tid >> 5;

    // ---- (1) issue all y halo loads into registers ----
    float yv[5][4];
    int   yoff[5];
    #pragma unroll
    for (int k = 0; k < 5; ++k) {
        int i = tid + k * 256;
        bool act = (i < NPIX * 2);
        int q  = i / NPIX;                   // 0/1 (channel quad)
        int px = i - q * NPIX;
        int r = px / TPX, col = px - r * TPX;
        int sy = by * TH + r - PADD, sx = bx * TW + col - PADD;
        bool ok = act && sy >= 0 && sy < HH && sx >= 0 && sx < WW;
        const float* yp = y + ((size_t)(b * DIMC + g * GCH + q * 4) * HH + sy) * WW + sx;
        #pragma unroll
        for (int j = 0; j < 4; ++j) yv[k][j] = ok ? yp[j * PLANE] : 0.f;
        yoff[k] = act ? (px * GCH + q * 4) : -1;
    }

    // ---- (2) issue xt B-fragment loads (stay resident) ----
    int gpix[4];
    #pragma unroll
    for (int nt = 0; nt < 4; ++nt) {
        int lp = w * 64 + nt * 16 + fr;
        gpix[nt] = (by * TH + (lp >> 5)) * WW + bx * TW + (lp & 31);
    }
    short8 bf[2][4];
    #pragma unroll
    for (int kp = 0; kp < 2; ++kp)
        #pragma unroll
        for (int nt = 0; nt < 4; ++nt) {
            union { uint4 u; short8 s; } cv;
            cv.u = *reinterpret_cast<const uint4*>(
                xt + (((size_t)b * 8 + kp * 4 + fk) * PLANE + gpix[nt]) * 8);
            bf[kp][nt] = cv.s;
        }

    // ---- (3) write ytile (waits only on y loads; xt loads still in flight) ----
    #pragma unroll
    for (int k = 0; k < 5; ++k) {
        if (yoff[k] >= 0) {
            *reinterpret_cast<uint2*>(&ytile[yoff[k]]) =
                make_uint2(pkh(yv[k][0], yv[k][1]), pkh(yv[k][2], yv[k][3]));
        }
    }

    // ---- (4) two super-chunks: GEMM 32 taps -> wtl -> involution partial ----
    __half2 acch[4];
    #pragma unroll
    for (int cc = 0; cc < 4; ++cc) acch[cc] = __float2half2_rn(0.f);
    const int ybase = (ty * TPX + tx) * GCH;           // half index of own tap origin

    #pragma unroll
    for (int mc = 0; mc < 2; ++mc) {
        // GEMM for taps mc*32 .. mc*32+31 (rows (mc*2+dm)*16+fr)
        f32x4 acc[2][4];
        #pragma unroll
        for (int dm = 0; dm < 2; ++dm)
            #pragma unroll
            for (int nt = 0; nt < 4; ++nt)
                acc[dm][nt] = f32x4{0.f, 0.f, 0.f, 0.f};

        #pragma unroll
        for (int dm = 0; dm < 2; ++dm) {
            short8 af[2];
            #pragma unroll
            for (int kp = 0; kp < 2; ++kp) {
                union { uint4 u; short8 s; } cv;
                cv.u = *reinterpret_cast<const uint4*>(
                    wc + ((size_t)(g * 64 + (mc * 2 + dm) * 16 + fr)) * DIMC + kp * 32 + fk * 8);
                af[kp] = cv.s;
            }
            #pragma unroll
            for (int kp = 0; kp < 2; ++kp)
                #pragma unroll
                for (int nt = 0; nt < 4; ++nt)
                    acc[dm][nt] = __builtin_amdgcn_mfma_f32_16x16x32_bf16(
                        af[kp], bf[kp][nt], acc[dm][nt], 0, 0, 0);
        }

        __syncthreads();   // mc=0: ytile+prev-none; mc=1: chunk-0 reads complete

        // bias + write super-chunk: tap t = dm*16 + fk*4 + j  (absolute kk = mc*32+t)
        #pragma unroll
        for (int dm = 0; dm < 2; ++dm) {
            int rb = (mc * 2 + dm) * 16 + fk * 4;
            float bb0 = bc[g * 64 + rb + 0], bb1 = bc[g * 64 + rb + 1];
            float bb2 = bc[g * 64 + rb + 2], bb3 = bc[g * 64 + rb + 3];
            #pragma unroll
            for (int nt = 0; nt < 4; ++nt) {
                int lp = w * 64 + nt * 16 + fr;
                *reinterpret_cast<uint2*>(&wtl[lp * WTSTR + dm * 16 + fk * 4]) =
                    make_uint2(pkh(acc[dm][nt][0] + bb0, acc[dm][nt][1] + bb1),
                               pkh(acc[dm][nt][2] + bb2, acc[dm][nt][3] + bb3));
            }
        }

        __syncthreads();   // chunk visible

        // read own 32 taps (8 x b64)
        uint2 wr[8];
        #pragma unroll
        for (int q = 0; q < 8; ++q)
            wr[q] = *reinterpret_cast<const uint2*>(&wtl[tid * WTSTR + q * 4]);

        // involution partial over this chunk's taps
        const int ninv = (mc == 0) ? 32 : 17;          // kk 0..31 / 32..48
        #pragma unroll
        for (int j = 0; j < 32; ++j) {
            if (j >= ninv) break;
            const int kk = mc * 32 + j;
            const int ky = kk / 7, kx = kk - ky * 7;
            unsigned uh = (j & 2) ? wr[j >> 2].y : wr[j >> 2].x;
            union { unsigned u; __half2 h; } hc; hc.u = uh;
            __half wh = (j & 1) ? __high2half(hc.h) : __low2half(hc.h);
            __half2 wv2 = __half2half2(wh);
            union { uint4 u; __half2 h[4]; } yvv;
            yvv.u = *reinterpret_cast<const uint4*>(&ytile[ybase + (ky * TPX + kx) * GCH]);
            acch[0] = __hfma2(wv2, yvv.h[0], acch[0]);
            acch[1] = __hfma2(wv2, yvv.h[1], acch[1]);
            acch[2] = __hfma2(wv2, yvv.h[2], acch[2]);
            acch[3] = __hfma2(wv2, yvv.h[3], acch[3]);
        }
    }

    const int gy = by * TH + ty, gx = bx * TW + tx;
    float* op = out + ((size_t)(b * DIMC + g * GCH) * HH + gy) * WW + gx;
    #pragma unroll
    for (int cc = 0; cc < 4; ++cc) {
        float2 f = __half22float2(acch[cc]);
        op[(2 * cc) * PLANE]     = f.x;
        op[(2 * cc + 1) * PLANE] = f.y;
    }
}

// ---------- Fallback (known-good R2 fused kernel) ----------
__global__ __launch_bounds__(256, 1)
void invol_fused_kernel(const float* __restrict__ x, const float* __restrict__ y,
                        const float* __restrict__ w1, const float* __restrict__ b1,
                        const float* __restrict__ w2, const float* __restrict__ b2,
                        float* __restrict__ out) {
    __shared__ float ytile[NPIX * CPAD];
    const int tid = threadIdx.x;
    const int tx = tid & 31, ty = tid >> 5;
    const int bx = blockIdx.x, by = blockIdx.y, bz = blockIdx.z;
    const int gx = bx * TW + tx, gy = by * TH + ty;

    float xv[DIMC];
    const float* xp = x + ((size_t)(bz * DIMC) * HH + gy) * WW + gx;
    #pragma unroll
    for (int c = 0; c < DIMC; ++c) xv[c] = xp[c * PLANE];

    float mid[CMID];
    #pragma unroll
    for (int m = 0; m < CMID; ++m) {
        float a = b1[m];
        const float4* w1r = reinterpret_cast<const float4*>(w1 + m * DIMC);
        #pragma unroll
        for (int cq = 0; cq < DIMC / 4; ++cq) {
            float4 wv = w1r[cq];
            a = fmaf(wv.x, xv[4*cq+0], a);
            a = fmaf(wv.y, xv[4*cq+1], a);
            a = fmaf(wv.z, xv[4*cq+2], a);
            a = fmaf(wv.w, xv[4*cq+3], a);
        }
        mid[m] = a;
    }

    for (int g = 0; g < NG; ++g) {
        __syncthreads();
        for (int i = tid; i < NPIX * GCH; i += 256) {
            int c = i / NPIX;
            int p = i - c * NPIX;
            int r = p / TPX;
            int col = p - r * TPX;
            int sy = by * TH + r - PADD;
            int sx = bx * TW + col - PADD;
            float v = 0.f;
            if (sy >= 0 && sy < HH && sx >= 0 && sx < WW)
                v = y[((size_t)(bz * DIMC + g * GCH + c) * HH + sy) * WW + sx];
            ytile[p * CPAD + c] = v;
        }
        __syncthreads();

        float wt[NTAP];
        const float*  b2g = b2 + g * NTAP;
        const float4* w2g = reinterpret_cast<const float4*>(w2 + g * NTAP * CMID);
        #pragma unroll
        for (int kk = 0; kk < NTAP; ++kk) {
            float a = b2g[kk];
            #pragma unroll
            for (int mq = 0; mq < CMID / 4; ++mq) {
                float4 wv = w2g[kk * (CMID / 4) + mq];
                a = fmaf(wv.x, mid[4*mq+0], a);
                a = fmaf(wv.y, mid[4*mq+1], a);
                a = fmaf(wv.z, mid[4*mq+2], a);
                a = fmaf(wv.w, mid[4*mq+3], a);
            }
            wt[kk] = a;
        }

        float acc[GCH];
        #pragma unroll
        for (int cc = 0; cc < GCH; ++cc) acc[cc] = 0.f;
        #pragma unroll
        for (int ky = 0; ky < KS; ++ky) {
            #pragma unroll
            for (int kx = 0; kx < KS; ++kx) {
                float wv = wt[ky * KS + kx];
                int pp = (ty + ky) * TPX + (tx + kx);
                const float4* yr = reinterpret_cast<const float4*>(&ytile[pp * CPAD]);
                float4 ya = yr[0];
                float4 yb = yr[1];
                acc[0] = fmaf(wv, ya.x, acc[0]);
                acc[1] = fmaf(wv, ya.y, acc[1]);
                acc[2] = fmaf(wv, ya.z, acc[2]);
                acc[3] = fmaf(wv, ya.w, acc[3]);
                acc[4] = fmaf(wv, yb.x, acc[4]);
                acc[5] = fmaf(wv, yb.y, acc[5]);
                acc[6] = fmaf(wv, yb.z, acc[6]);
                acc[7] = fmaf(wv, yb.w, acc[7]);
            }
        }

        float* op = out + ((size_t)(bz * DIMC + g * GCH) * HH + gy) * WW + gx;
        #pragma unroll
        for (int cc = 0; cc < GCH; ++cc) op[cc * PLANE] = acc[cc];
    }
}

extern "C" void kernel_launch(void* const* d_in, const int* in_sizes, int n_in,
                              void* d_out, int out_size, void* d_ws, size_t ws_size,
                              hipStream_t stream) {
    const float* x  = (const float*)d_in[0];
    const float* y  = (const float*)d_in[1];
    const float* w1 = (const float*)d_in[2];
    const float* b1 = (const float*)d_in[3];
    const float* w2 = (const float*)d_in[4];
    const float* b2 = (const float*)d_in[5];
    float* out = (float*)d_out;

    if (ws_size >= WS_NEED) {
        char* ws = (char*)d_ws;
        unsigned short* wcp = (unsigned short*)(ws + WC_OFF);
        float*          bcp = (float*)(ws + BC_OFF);
        unsigned short* xtp = (unsigned short*)(ws + XT_OFF);

        hipLaunchKernelGGL(prep_all, dim3(512 + 32), dim3(256), 0, stream,
                           x, w1, b1, w2, b2, wcp, bcp, xtp);
        hipLaunchKernelGGL(invol_mfma4_kernel, dim3(WW / TW, HH / TH, NB * NG), dim3(256), 0, stream,
                           y, xtp, wcp, bcp, out);
    } else {
        dim3 grid(WW / TW, HH / TH, NB);
        hipLaunchKernelGGL(invol_fused_kernel, grid, dim3(256), 0, stream,
                           x, y, w1, b1, w2, b2, out);
    }
}